// Round 1
// baseline (1905.256 us; speedup 1.0000x reference)
//
#include <hip/hip_runtime.h>

#define NREL 3

// ---------------------------------------------------------------------------
// K1: build per-combo tables.
//   x1[combo]        = relu(pre_w[shape] + pre_w[8+color] + pre_b)      [64][32]
//   root1t[combo]    = x1[combo] @ conv1_root + conv1_b                 [64][64]
//   msg1t[r][combo]  = x1[combo] @ conv1_w[r]                           [3][64][64]
// grid 64 (one block per combo), block 64 (one thread per out dim)
// ---------------------------------------------------------------------------
__global__ void build_tables(const float* __restrict__ pre_w, const float* __restrict__ pre_b,
                             const float* __restrict__ w1, const float* __restrict__ root1,
                             const float* __restrict__ b1,
                             float* __restrict__ root1t, float* __restrict__ msg1t) {
    int combo = blockIdx.x;          // 0..63
    int j = threadIdx.x;             // 0..63
    __shared__ float x1s[32];
    int s = combo >> 3, c = combo & 7;
    if (j < 32) {
        float v = pre_w[s * 32 + j] + pre_w[(8 + c) * 32 + j] + pre_b[j];
        x1s[j] = v > 0.f ? v : 0.f;
    }
    __syncthreads();
    float acc = b1[j];
#pragma unroll
    for (int k = 0; k < 32; ++k) acc = fmaf(x1s[k], root1[k * 64 + j], acc);
    root1t[combo * 64 + j] = acc;
    for (int r = 0; r < NREL; ++r) {
        float a = 0.f;
#pragma unroll
        for (int k = 0; k < 32; ++k) a = fmaf(x1s[k], w1[(r * 32 + k) * 64 + j], a);
        msg1t[(r * 64 + combo) * 64 + j] = a;
    }
}

// ---------------------------------------------------------------------------
// K2: per-(dst,rel) incoming-edge counts (into cnt, later inverted in place)
// ---------------------------------------------------------------------------
__global__ void count_edges(const int* __restrict__ ei, const int* __restrict__ et,
                            float* __restrict__ cnt, int E) {
    int e = blockIdx.x * blockDim.x + threadIdx.x;
    if (e < E) {
        int d = ei[E + e], r = et[e];
        atomicAdd(&cnt[d * NREL + r], 1.0f);
    }
}

// K3: cnt -> 1/max(cnt,1) with 0 for empty (empty segments contribute 0 anyway)
__global__ void invert_cnt(float* __restrict__ cnt, int n) {
    int i = blockIdx.x * blockDim.x + threadIdx.x;
    if (i < n) { float v = cnt[i]; cnt[i] = v > 0.f ? 1.f / v : 0.f; }
}

// ---------------------------------------------------------------------------
// K4: h1[i] = root1t[combo(i)]   (root contribution + bias, pre-aggregation)
// ---------------------------------------------------------------------------
__global__ void init_h1(const int* __restrict__ node_x, const float* __restrict__ root1t,
                        float* __restrict__ h1, int N) {
    int t = blockIdx.x * blockDim.x + threadIdx.x;
    int i = t >> 6, j = t & 63;
    if (i < N) {
        int combo = node_x[i * 2] * 8 + node_x[i * 2 + 1];
        h1[i * 64 + j] = root1t[combo * 64 + j];
    }
}

// ---------------------------------------------------------------------------
// K5: conv1 edge pass. One 64-lane wave per edge; message is a table row.
//   h1[dst] += msg1t[r][combo(src)] * invcnt[dst][r]
// msg table staged in LDS (48 KB), grid-stride to amortize the fill.
// ---------------------------------------------------------------------------
__global__ void __launch_bounds__(256) conv1_edges(
        const int* __restrict__ ei, const int* __restrict__ et,
        const int* __restrict__ node_x, const float* __restrict__ invcnt,
        const float* __restrict__ msg1t, float* __restrict__ h1, int E) {
    __shared__ float tab[NREL * 64 * 64];
    for (int t = threadIdx.x; t < NREL * 64 * 64; t += 256) tab[t] = msg1t[t];
    __syncthreads();
    int lane = threadIdx.x & 63;
    int grp  = threadIdx.x >> 6;      // 4 waves/block, one edge each per iter
    int nGrp = (E + 3) >> 2;
    for (int g = blockIdx.x; g < nGrp; g += gridDim.x) {
        int e = g * 4 + grp;
        if (e < E) {
            int s = ei[e], d = ei[E + e], r = et[e];
            int combo = node_x[s * 2] * 8 + node_x[s * 2 + 1];
            float scale = invcnt[d * NREL + r];
            float v = tab[(r * 64 + combo) * 64 + lane] * scale;
            atomicAdd(&h1[d * 64 + lane], v);
        }
    }
}

// K6: in-place ReLU
__global__ void relu_ip(float* __restrict__ x, int n) {
    int i = blockIdx.x * blockDim.x + threadIdx.x;
    if (i < n) { float v = x[i]; x[i] = v > 0.f ? v : 0.f; }
}

// ---------------------------------------------------------------------------
// K7: h2[i] = conv2_b + h1[i] @ conv2_root   (root contribution)
// 4 nodes/block; h1 row via broadcast float4 loads; root2 (16 KB) stays in L1.
// ---------------------------------------------------------------------------
__global__ void __launch_bounds__(256) conv2_root(
        const float* __restrict__ h1, const float* __restrict__ root2,
        const float* __restrict__ b2, float* __restrict__ h2, int N) {
    int i = blockIdx.x * 4 + (threadIdx.x >> 6);
    int j = threadIdx.x & 63;
    if (i >= N) return;
    const float4* row = (const float4*)(h1 + (size_t)i * 64);
    float acc = b2[j];
#pragma unroll
    for (int k4 = 0; k4 < 16; ++k4) {
        float4 hv = row[k4];
        acc = fmaf(hv.x, root2[(k4 * 4 + 0) * 64 + j], acc);
        acc = fmaf(hv.y, root2[(k4 * 4 + 1) * 64 + j], acc);
        acc = fmaf(hv.z, root2[(k4 * 4 + 2) * 64 + j], acc);
        acc = fmaf(hv.w, root2[(k4 * 4 + 3) * 64 + j], acc);
    }
    h2[(size_t)i * 64 + j] = acc;
}

// ---------------------------------------------------------------------------
// K8: conv2 edge pass for one relation r. One wave per edge (skips other
// relations). Each lane holds its W-column (64 VGPRs, statically indexed);
// h1[src] row read as 16 broadcast float4s. h2[dst] += (h1[src]@W_r)*scale.
// ---------------------------------------------------------------------------
__global__ void __launch_bounds__(256) conv2_edges(
        const int* __restrict__ ei, const int* __restrict__ et,
        const float* __restrict__ h1, const float* __restrict__ invcnt,
        const float* __restrict__ w2, float* __restrict__ h2, int E, int r) {
    int lane = threadIdx.x & 63;
    int grp  = threadIdx.x >> 6;
    float wcol[64];
#pragma unroll
    for (int k = 0; k < 64; ++k) wcol[k] = w2[(r * 64 + k) * 64 + lane];
    int nGrp = (E + 3) >> 2;
    for (int g = blockIdx.x; g < nGrp; g += gridDim.x) {
        int e = g * 4 + grp;
        if (e >= E) continue;
        if (et[e] != r) continue;
        int s = ei[e], d = ei[E + e];
        const float4* row = (const float4*)(h1 + (size_t)s * 64);
        float acc = 0.f;
#pragma unroll
        for (int k4 = 0; k4 < 16; ++k4) {
            float4 hv = row[k4];
            acc = fmaf(hv.x, wcol[4 * k4 + 0], acc);
            acc = fmaf(hv.y, wcol[4 * k4 + 1], acc);
            acc = fmaf(hv.z, wcol[4 * k4 + 2], acc);
            acc = fmaf(hv.w, wcol[4 * k4 + 3], acc);
        }
        atomicAdd(&h2[(size_t)d * 64 + lane], acc * invcnt[d * NREL + r]);
    }
}

// ---------------------------------------------------------------------------
// K9: mean-pool (batch is sorted -> binary search segment) + classifier.
// ReLU of h2 folded in. One block (1 wave) per graph.
// ---------------------------------------------------------------------------
__global__ void __launch_bounds__(64) pool_cls(
        const float* __restrict__ h2, const int* __restrict__ batch,
        const float* __restrict__ cls_w, const float* __restrict__ cls_b,
        float* __restrict__ out, int N, int G) {
    int g = blockIdx.x;
    int lane = threadIdx.x;
    auto lb = [&](int key) {
        int lo = 0, hi = N;
        while (lo < hi) { int mid = (lo + hi) >> 1; if (batch[mid] < key) lo = mid + 1; else hi = mid; }
        return lo;
    };
    int start = lb(g), end = lb(g + 1);
    float sum = 0.f;
    for (int i = start; i < end; ++i) {
        float v = h2[(size_t)i * 64 + lane];
        sum += v > 0.f ? v : 0.f;
    }
    int cntn = end - start;
    float pooled = sum / (float)(cntn > 0 ? cntn : 1);
    __shared__ float ps[64];
    ps[lane] = pooled;
    __syncthreads();
    if (lane < 10) {
        float o = cls_b[lane];
#pragma unroll
        for (int j = 0; j < 64; ++j) o = fmaf(ps[j], cls_w[j * 10 + lane], o);
        out[g * 10 + lane] = o;
    }
}

// ---------------------------------------------------------------------------
extern "C" void kernel_launch(void* const* d_in, const int* in_sizes, int n_in,
                              void* d_out, int out_size, void* d_ws, size_t ws_size,
                              hipStream_t stream) {
    const int*   node_x = (const int*)d_in[0];
    const int*   ei     = (const int*)d_in[1];   // [2,E]
    const int*   et     = (const int*)d_in[2];   // [E]
    const int*   batch  = (const int*)d_in[3];   // [N]
    const float* pre_w  = (const float*)d_in[4];
    const float* pre_b  = (const float*)d_in[5];
    const float* w1     = (const float*)d_in[6];
    const float* root1  = (const float*)d_in[7];
    const float* b1     = (const float*)d_in[8];
    const float* w2     = (const float*)d_in[9];
    const float* root2  = (const float*)d_in[10];
    const float* b2     = (const float*)d_in[11];
    const float* cls_w  = (const float*)d_in[12];
    const float* cls_b  = (const float*)d_in[13];
    float* out = (float*)d_out;

    int N = in_sizes[0] / 2;
    int E = in_sizes[1] / 2;
    int G = out_size / 10;

    char* ws = (char*)d_ws;
    size_t off = 0;
    auto alloc = [&](size_t bytes) {
        void* p = ws + off;
        off = (off + bytes + 255) & ~(size_t)255;
        return p;
    };
    float* root1t = (float*)alloc(64 * 64 * sizeof(float));
    float* msg1t  = (float*)alloc(NREL * 64 * 64 * sizeof(float));
    float* invcnt = (float*)alloc((size_t)N * NREL * sizeof(float));
    float* h1     = (float*)alloc((size_t)N * 64 * sizeof(float));
    float* h2     = (float*)alloc((size_t)N * 64 * sizeof(float));

    hipMemsetAsync(invcnt, 0, (size_t)N * NREL * sizeof(float), stream);

    build_tables<<<64, 64, 0, stream>>>(pre_w, pre_b, w1, root1, b1, root1t, msg1t);
    count_edges<<<(E + 255) / 256, 256, 0, stream>>>(ei, et, invcnt, E);
    invert_cnt<<<(N * NREL + 255) / 256, 256, 0, stream>>>(invcnt, N * NREL);
    init_h1<<<(N * 64 + 255) / 256, 256, 0, stream>>>(node_x, root1t, h1, N);
    conv1_edges<<<2048, 256, 0, stream>>>(ei, et, node_x, invcnt, msg1t, h1, E);
    relu_ip<<<(N * 64 + 255) / 256, 256, 0, stream>>>(h1, N * 64);
    conv2_root<<<(N + 3) / 4, 256, 0, stream>>>(h1, root2, b2, h2, N);
    for (int r = 0; r < NREL; ++r)
        conv2_edges<<<2048, 256, 0, stream>>>(ei, et, h1, invcnt, w2, h2, E, r);
    pool_cls<<<G, 64, 0, stream>>>(h2, batch, cls_w, cls_b, out, N, G);
}

// Round 2
// 331.093 us; speedup vs baseline: 5.7544x; 5.7544x over previous
//
#include <hip/hip_runtime.h>
#include <hip/hip_bf16.h>

#define NREL 3

typedef __attribute__((ext_vector_type(8))) short short8;
typedef __attribute__((ext_vector_type(4))) float floatx4;

static __device__ inline float bf2f(unsigned short u) {
    union { unsigned int i; float f; } v; v.i = ((unsigned int)u) << 16; return v.f;
}
static __device__ inline unsigned short f2bf(float f) {
    union { float f; unsigned int i; } v; v.f = f;
    unsigned int x = v.i;
    return (unsigned short)((x + 0x7FFF + ((x >> 16) & 1)) >> 16);  // RNE
}

// ---------------------------------------------------------------------------
// K1: per-combo tables. x1tab[64][32], root1t[64][64] (= x1@root1 + b1)
// ---------------------------------------------------------------------------
__global__ void build_tables(const float* __restrict__ pre_w, const float* __restrict__ pre_b,
                             const float* __restrict__ root1, const float* __restrict__ b1,
                             float* __restrict__ x1tab, float* __restrict__ root1t) {
    int combo = blockIdx.x, j = threadIdx.x;
    __shared__ float x1s[32];
    int s = combo >> 3, c = combo & 7;
    if (j < 32) {
        float v = pre_w[s * 32 + j] + pre_w[(8 + c) * 32 + j] + pre_b[j];
        v = v > 0.f ? v : 0.f;
        x1s[j] = v;
        x1tab[combo * 32 + j] = v;
    }
    __syncthreads();
    float acc = b1[j];
#pragma unroll
    for (int k = 0; k < 32; ++k) acc = fmaf(x1s[k], root1[k * 64 + j], acc);
    root1t[combo * 64 + j] = acc;
}

// ---------------------------------------------------------------------------
// K2: pre-shuffle weights into MFMA B-fragment layout (bf16).
//   B1f[(nt*3+kt)*64 + l][0..7] = W1cat[kt*32 + (l>>4)*8 + i][nt*16 + (l&15)]
//   B2f[(nt*8+kt)*64 + l][0..7] = [root2;W2cat][ ... ]
// ---------------------------------------------------------------------------
__global__ void prep_B(const float* __restrict__ w1, const float* __restrict__ root2,
                       const float* __restrict__ w2,
                       unsigned short* __restrict__ B1f, unsigned short* __restrict__ B2f) {
    int t = blockIdx.x * blockDim.x + threadIdx.x;
    if (t < 4 * 8 * 64 * 8) {
        int i = t & 7, l = (t >> 3) & 63, kt = (t >> 9) & 7, nt = t >> 12;
        int k = kt * 32 + ((l >> 4) * 8) + i;
        int col = nt * 16 + (l & 15);
        float v = (k < 64) ? root2[k * 64 + col] : w2[(k - 64) * 64 + col];
        B2f[t] = f2bf(v);
    }
    if (t < 4 * 3 * 64 * 8) {
        int i = t & 7, l = (t >> 3) & 63;
        int rest = t >> 9;
        int kt = rest % 3, nt = rest / 3;
        int k = kt * 32 + ((l >> 4) * 8) + i;
        int col = nt * 16 + (l & 15);
        B1f[t] = f2bf(w1[k * 64 + col]);
    }
}

// K3: combo[i]
__global__ void combo_kernel(const int* __restrict__ node_x, int* __restrict__ combo, int N) {
    int i = blockIdx.x * blockDim.x + threadIdx.x;
    if (i < N) combo[i] = node_x[2 * i] * 8 + node_x[2 * i + 1];
}

// K4: per-(dst,rel) counts (int atomics)
__global__ void count_edges(const int* __restrict__ ei, const int* __restrict__ et,
                            int* __restrict__ cnt_rel, int E) {
    int e = blockIdx.x * blockDim.x + threadIdx.x;
    if (e < E) atomicAdd(&cnt_rel[ei[E + e] * NREL + et[e]], 1);
}

// K5a/b/c: exclusive scan of degrees -> rowptr[N+1]
__global__ void scan_block(const int* __restrict__ cnt_rel, int* __restrict__ rowptr,
                           int* __restrict__ bsums, int Np1) {
    __shared__ int s[1024];
    int i = blockIdx.x * 1024 + threadIdx.x;
    int d = 0;
    if (i < Np1 - 1) d = cnt_rel[i * 3] + cnt_rel[i * 3 + 1] + cnt_rel[i * 3 + 2];
    s[threadIdx.x] = d;
    __syncthreads();
    for (int off = 1; off < 1024; off <<= 1) {
        int v = (threadIdx.x >= off) ? s[threadIdx.x - off] : 0;
        __syncthreads();
        s[threadIdx.x] += v;
        __syncthreads();
    }
    if (i < Np1) rowptr[i] = s[threadIdx.x] - d;
    if (threadIdx.x == 1023) bsums[blockIdx.x] = s[1023];
}
__global__ void scan_bsums(int* __restrict__ bsums, int nb) {
    __shared__ int s[128];
    int v = (threadIdx.x < nb) ? bsums[threadIdx.x] : 0;
    s[threadIdx.x] = v;
    __syncthreads();
    for (int off = 1; off < 128; off <<= 1) {
        int u = (threadIdx.x >= off) ? s[threadIdx.x - off] : 0;
        __syncthreads();
        s[threadIdx.x] += u;
        __syncthreads();
    }
    if (threadIdx.x < nb) bsums[threadIdx.x] = s[threadIdx.x] - v;
}
__global__ void scan_add(int* __restrict__ rowptr, const int* __restrict__ bsums, int Np1) {
    int i = blockIdx.x * 1024 + threadIdx.x;
    if (i < Np1) rowptr[i] += bsums[blockIdx.x];
}

// K6: invcnt[i][r] = cnt>0 ? 1/cnt : 0
__global__ void invert_cnt(const int* __restrict__ cnt_rel, float* __restrict__ invcnt, int n) {
    int i = blockIdx.x * blockDim.x + threadIdx.x;
    if (i < n) { int c = cnt_rel[i]; invcnt[i] = c > 0 ? 1.f / (float)c : 0.f; }
}

// K7: scatter edges into CSR buckets, packed (rel<<17)|src
__global__ void scatter_edges(const int* __restrict__ ei, const int* __restrict__ et,
                              const int* __restrict__ rowptr, int* __restrict__ cursor,
                              unsigned int* __restrict__ edges_packed, int E) {
    int e = blockIdx.x * blockDim.x + threadIdx.x;
    if (e < E) {
        int d = ei[E + e];
        int slot = rowptr[d] + atomicAdd(&cursor[d], 1);
        edges_packed[slot] = ((unsigned)et[e] << 17) | (unsigned)ei[e];
    }
}

// ---------------------------------------------------------------------------
// K8: conv1 aggregation. Wave per node; lanes = 2 halves x 32 dims.
//   AGG1[i][r*32+k] = invcnt[i][r] * sum_{e in bucket, rel=r} x1tab[combo[src]][k]
// ---------------------------------------------------------------------------
__global__ void __launch_bounds__(256) agg1_kernel(
        const unsigned int* __restrict__ edges, const int* __restrict__ rowptr,
        const int* __restrict__ combo, const float* __restrict__ x1tab,
        const float* __restrict__ invcnt, unsigned short* __restrict__ AGG1, int N) {
    __shared__ float tab[64 * 32];
    for (int t = threadIdx.x; t < 64 * 32; t += 256) tab[t] = x1tab[t];
    __syncthreads();
    int i = blockIdx.x * 4 + (threadIdx.x >> 6);
    if (i >= N) return;
    int lane = threadIdx.x & 63;
    int k = lane & 31, half = lane >> 5;
    int e1 = rowptr[i + 1];
    float a0 = 0.f, a1 = 0.f, a2 = 0.f;
    for (int e = rowptr[i] + half; e < e1; e += 2) {
        unsigned p = edges[e];
        int src = p & 0x1FFFF, r = p >> 17;
        float v = tab[combo[src] * 32 + k];
        a0 += (r == 0) ? v : 0.f;
        a1 += (r == 1) ? v : 0.f;
        a2 += (r == 2) ? v : 0.f;
    }
    a0 += __shfl_xor(a0, 32);
    a1 += __shfl_xor(a1, 32);
    a2 += __shfl_xor(a2, 32);
    if (half == 0) {
        AGG1[i * 96 + k]      = f2bf(a0 * invcnt[i * 3 + 0]);
        AGG1[i * 96 + 32 + k] = f2bf(a1 * invcnt[i * 3 + 1]);
        AGG1[i * 96 + 64 + k] = f2bf(a2 * invcnt[i * 3 + 2]);
    }
}

// ---------------------------------------------------------------------------
// K9: conv1 transform. MFMA [16,96]@[96,64] per wave + root-table epilogue.
//   h1 = relu(root1t[combo] + AGG1 @ W1cat)   -> bf16
// ---------------------------------------------------------------------------
__global__ void __launch_bounds__(256) gemm1_kernel(
        const unsigned short* __restrict__ AGG1, const unsigned short* __restrict__ B1f,
        const float* __restrict__ root1t, const int* __restrict__ combo,
        unsigned short* __restrict__ h1, int N) {
    int g = blockIdx.x * 4 + (threadIdx.x >> 6);
    int node0 = g * 16;
    if (node0 >= N) return;
    int lane = threadIdx.x & 63;
    int m = lane & 15, kg = lane >> 4;
    short8 a[3];
#pragma unroll
    for (int kt = 0; kt < 3; ++kt)
        a[kt] = *(const short8*)(AGG1 + (size_t)(node0 + m) * 96 + kt * 32 + kg * 8);
#pragma unroll
    for (int nt = 0; nt < 4; ++nt) {
        floatx4 c = {0.f, 0.f, 0.f, 0.f};
#pragma unroll
        for (int kt = 0; kt < 3; ++kt) {
            short8 b = *(const short8*)(B1f + ((nt * 3 + kt) * 64 + lane) * 8);
            c = __builtin_amdgcn_mfma_f32_16x16x32_bf16(a[kt], b, c, 0, 0, 0);
        }
#pragma unroll
        for (int q = 0; q < 4; ++q) {
            int node = node0 + kg * 4 + q;
            float v = c[q] + root1t[combo[node] * 64 + nt * 16 + m];
            v = v > 0.f ? v : 0.f;
            h1[(size_t)node * 64 + nt * 16 + m] = f2bf(v);
        }
    }
}

// ---------------------------------------------------------------------------
// K10: conv2 aggregation. Wave per node, lane = dim. Gathers bf16 h1 rows.
//   AGG2[i][r*64+l] = invcnt[i][r] * sum_{rel=r} h1[src][l]
// ---------------------------------------------------------------------------
__global__ void __launch_bounds__(256) agg2_kernel(
        const unsigned int* __restrict__ edges, const int* __restrict__ rowptr,
        const unsigned short* __restrict__ h1, const float* __restrict__ invcnt,
        unsigned short* __restrict__ AGG2, int N) {
    int i = blockIdx.x * 4 + (threadIdx.x >> 6);
    if (i >= N) return;
    int lane = threadIdx.x & 63;
    int e0 = rowptr[i], e1 = rowptr[i + 1];
    float a0 = 0.f, a1 = 0.f, a2 = 0.f;
    int e = e0;
    for (; e + 4 <= e1; e += 4) {
        unsigned p0 = edges[e], p1 = edges[e + 1], p2 = edges[e + 2], p3 = edges[e + 3];
        float v0 = bf2f(h1[(size_t)(p0 & 0x1FFFF) * 64 + lane]);
        float v1 = bf2f(h1[(size_t)(p1 & 0x1FFFF) * 64 + lane]);
        float v2 = bf2f(h1[(size_t)(p2 & 0x1FFFF) * 64 + lane]);
        float v3 = bf2f(h1[(size_t)(p3 & 0x1FFFF) * 64 + lane]);
        int r0 = p0 >> 17, r1 = p1 >> 17, r2 = p2 >> 17, r3 = p3 >> 17;
        a0 += (r0 == 0) ? v0 : 0.f; a1 += (r0 == 1) ? v0 : 0.f; a2 += (r0 == 2) ? v0 : 0.f;
        a0 += (r1 == 0) ? v1 : 0.f; a1 += (r1 == 1) ? v1 : 0.f; a2 += (r1 == 2) ? v1 : 0.f;
        a0 += (r2 == 0) ? v2 : 0.f; a1 += (r2 == 1) ? v2 : 0.f; a2 += (r2 == 2) ? v2 : 0.f;
        a0 += (r3 == 0) ? v3 : 0.f; a1 += (r3 == 1) ? v3 : 0.f; a2 += (r3 == 2) ? v3 : 0.f;
    }
    for (; e < e1; ++e) {
        unsigned p = edges[e];
        float v = bf2f(h1[(size_t)(p & 0x1FFFF) * 64 + lane]);
        int r = p >> 17;
        a0 += (r == 0) ? v : 0.f; a1 += (r == 1) ? v : 0.f; a2 += (r == 2) ? v : 0.f;
    }
    AGG2[(size_t)i * 192 + lane]       = f2bf(a0 * invcnt[i * 3 + 0]);
    AGG2[(size_t)i * 192 + 64 + lane]  = f2bf(a1 * invcnt[i * 3 + 1]);
    AGG2[(size_t)i * 192 + 128 + lane] = f2bf(a2 * invcnt[i * 3 + 2]);
}

// ---------------------------------------------------------------------------
// K11: conv2 transform. MFMA [16,256]@[256,64]; K-tiles 0-1 read h1 (root),
// 2-7 read AGG2. Epilogue + b2, write bf16 h2 (relu deferred to pool).
// ---------------------------------------------------------------------------
__global__ void __launch_bounds__(256) gemm2_kernel(
        const unsigned short* __restrict__ h1, const unsigned short* __restrict__ AGG2,
        const unsigned short* __restrict__ B2f, const float* __restrict__ b2,
        unsigned short* __restrict__ h2, int N) {
    int g = blockIdx.x * 4 + (threadIdx.x >> 6);
    int node0 = g * 16;
    if (node0 >= N) return;
    int lane = threadIdx.x & 63;
    int m = lane & 15, kg = lane >> 4;
    short8 a[8];
#pragma unroll
    for (int kt = 0; kt < 2; ++kt)
        a[kt] = *(const short8*)(h1 + (size_t)(node0 + m) * 64 + kt * 32 + kg * 8);
#pragma unroll
    for (int kt = 2; kt < 8; ++kt)
        a[kt] = *(const short8*)(AGG2 + (size_t)(node0 + m) * 192 + (kt - 2) * 32 + kg * 8);
#pragma unroll
    for (int nt = 0; nt < 4; ++nt) {
        floatx4 c = {0.f, 0.f, 0.f, 0.f};
#pragma unroll
        for (int kt = 0; kt < 8; ++kt) {
            short8 b = *(const short8*)(B2f + ((nt * 8 + kt) * 64 + lane) * 8);
            c = __builtin_amdgcn_mfma_f32_16x16x32_bf16(a[kt], b, c, 0, 0, 0);
        }
        float bias = b2[nt * 16 + m];
#pragma unroll
        for (int q = 0; q < 4; ++q) {
            int node = node0 + kg * 4 + q;
            h2[(size_t)node * 64 + nt * 16 + m] = f2bf(c[q] + bias);
        }
    }
}

// ---------------------------------------------------------------------------
// K12: mean-pool (sorted batch -> binary search) + classifier; relu folded.
// ---------------------------------------------------------------------------
__global__ void __launch_bounds__(64) pool_cls(
        const unsigned short* __restrict__ h2, const int* __restrict__ batch,
        const float* __restrict__ cls_w, const float* __restrict__ cls_b,
        float* __restrict__ out, int N, int G) {
    int g = blockIdx.x, lane = threadIdx.x;
    auto lb = [&](int key) {
        int lo = 0, hi = N;
        while (lo < hi) { int mid = (lo + hi) >> 1; if (batch[mid] < key) lo = mid + 1; else hi = mid; }
        return lo;
    };
    int start = lb(g), end = lb(g + 1);
    float sum = 0.f;
    for (int i = start; i < end; ++i) {
        float v = bf2f(h2[(size_t)i * 64 + lane]);
        sum += v > 0.f ? v : 0.f;
    }
    int cntn = end - start;
    float pooled = sum / (float)(cntn > 0 ? cntn : 1);
    __shared__ float ps[64];
    ps[lane] = pooled;
    __syncthreads();
    if (lane < 10) {
        float o = cls_b[lane];
#pragma unroll
        for (int j = 0; j < 64; ++j) o = fmaf(ps[j], cls_w[j * 10 + lane], o);
        out[g * 10 + lane] = o;
    }
}

// ---------------------------------------------------------------------------
extern "C" void kernel_launch(void* const* d_in, const int* in_sizes, int n_in,
                              void* d_out, int out_size, void* d_ws, size_t ws_size,
                              hipStream_t stream) {
    const int*   node_x = (const int*)d_in[0];
    const int*   ei     = (const int*)d_in[1];
    const int*   et     = (const int*)d_in[2];
    const int*   batch  = (const int*)d_in[3];
    const float* pre_w  = (const float*)d_in[4];
    const float* pre_b  = (const float*)d_in[5];
    const float* w1     = (const float*)d_in[6];
    const float* root1  = (const float*)d_in[7];
    const float* b1     = (const float*)d_in[8];
    const float* w2     = (const float*)d_in[9];
    const float* root2  = (const float*)d_in[10];
    const float* b2     = (const float*)d_in[11];
    const float* cls_w  = (const float*)d_in[12];
    const float* cls_b  = (const float*)d_in[13];
    float* out = (float*)d_out;

    int N = in_sizes[0] / 2;
    int E = in_sizes[1] / 2;
    int G = out_size / 10;

    char* ws = (char*)d_ws;
    size_t off = 0;
    auto alloc = [&](size_t bytes) {
        void* p = ws + off;
        off = (off + bytes + 255) & ~(size_t)255;
        return p;
    };
    float*          x1tab  = (float*)alloc(64 * 32 * sizeof(float));
    float*          root1t = (float*)alloc(64 * 64 * sizeof(float));
    unsigned short* B1f    = (unsigned short*)alloc(4 * 3 * 64 * 8 * sizeof(short));
    unsigned short* B2f    = (unsigned short*)alloc(4 * 8 * 64 * 8 * sizeof(short));
    int*            cnt_rel= (int*)alloc((size_t)N * NREL * sizeof(int));
    float*          invcnt = (float*)alloc((size_t)N * NREL * sizeof(float));
    int*            rowptr = (int*)alloc((size_t)(N + 1) * sizeof(int));
    int*            cursor = (int*)alloc((size_t)N * sizeof(int));
    int*            bsums  = (int*)alloc(128 * sizeof(int));
    int*            combo  = (int*)alloc((size_t)N * sizeof(int));
    unsigned int*   edges  = (unsigned int*)alloc((size_t)E * sizeof(unsigned int));
    unsigned short* h1     = (unsigned short*)alloc((size_t)N * 64 * sizeof(short));
    unsigned short* h2     = (unsigned short*)alloc((size_t)N * 64 * sizeof(short));
    unsigned short* AGGbuf = (unsigned short*)alloc((size_t)N * 192 * sizeof(short));
    unsigned short* AGG1 = AGGbuf;   // [N][96], dead before AGG2 written
    unsigned short* AGG2 = AGGbuf;   // [N][192]

    hipMemsetAsync(cnt_rel, 0, (size_t)N * NREL * sizeof(int), stream);
    hipMemsetAsync(cursor, 0, (size_t)N * sizeof(int), stream);

    build_tables<<<64, 64, 0, stream>>>(pre_w, pre_b, root1, b1, x1tab, root1t);
    prep_B<<<64, 256, 0, stream>>>(w1, root2, w2, B1f, B2f);
    combo_kernel<<<(N + 255) / 256, 256, 0, stream>>>(node_x, combo, N);
    count_edges<<<(E + 255) / 256, 256, 0, stream>>>(ei, et, cnt_rel, E);

    int Np1 = N + 1;
    int nb = (Np1 + 1023) / 1024;
    scan_block<<<nb, 1024, 0, stream>>>(cnt_rel, rowptr, bsums, Np1);
    scan_bsums<<<1, 128, 0, stream>>>(bsums, nb);
    scan_add<<<nb, 1024, 0, stream>>>(rowptr, bsums, Np1);

    invert_cnt<<<(N * NREL + 255) / 256, 256, 0, stream>>>(cnt_rel, invcnt, N * NREL);
    scatter_edges<<<(E + 255) / 256, 256, 0, stream>>>(ei, et, rowptr, cursor, edges, E);

    agg1_kernel<<<(N + 3) / 4, 256, 0, stream>>>(edges, rowptr, combo, x1tab, invcnt, AGG1, N);
    gemm1_kernel<<<(N / 16 + 3) / 4, 256, 0, stream>>>(AGG1, B1f, root1t, combo, h1, N);
    agg2_kernel<<<(N + 3) / 4, 256, 0, stream>>>(edges, rowptr, h1, invcnt, AGG2, N);
    gemm2_kernel<<<(N / 16 + 3) / 4, 256, 0, stream>>>(h1, AGG2, B2f, b2, h2, N);
    pool_cls<<<G, 64, 0, stream>>>(h2, batch, cls_w, cls_b, out, N, G);
}

// Round 3
// 253.897 us; speedup vs baseline: 7.5040x; 1.3040x over previous
//
#include <hip/hip_runtime.h>

#define NREL 3
#define BSH 9              // 512 nodes per bucket
#define BNODES 512
#define NBLK_A 256         // blocks in hist/place passes

typedef __attribute__((ext_vector_type(8))) short short8;
typedef __attribute__((ext_vector_type(4))) float floatx4;

static __device__ inline float bf2f(unsigned short u) {
    union { unsigned int i; float f; } v; v.i = ((unsigned int)u) << 16; return v.f;
}
static __device__ inline unsigned short f2bf(float f) {
    union { float f; unsigned int i; } v; v.f = f;
    unsigned int x = v.i;
    return (unsigned short)((x + 0x7FFF + ((x >> 16) & 1)) >> 16);  // RNE
}

// ---------------------------------------------------------------------------
// K1: per-combo tables. x1tab[64][32], root1t[64][64] (= x1@root1 + b1)
// ---------------------------------------------------------------------------
__global__ void build_tables(const float* __restrict__ pre_w, const float* __restrict__ pre_b,
                             const float* __restrict__ root1, const float* __restrict__ b1,
                             float* __restrict__ x1tab, float* __restrict__ root1t) {
    int combo = blockIdx.x, j = threadIdx.x;
    __shared__ float x1s[32];
    int s = combo >> 3, c = combo & 7;
    if (j < 32) {
        float v = pre_w[s * 32 + j] + pre_w[(8 + c) * 32 + j] + pre_b[j];
        v = v > 0.f ? v : 0.f;
        x1s[j] = v;
        x1tab[combo * 32 + j] = v;
    }
    __syncthreads();
    float acc = b1[j];
#pragma unroll
    for (int k = 0; k < 32; ++k) acc = fmaf(x1s[k], root1[k * 64 + j], acc);
    root1t[combo * 64 + j] = acc;
}

// ---------------------------------------------------------------------------
// K2: pre-shuffle weights into MFMA B-fragment layout (bf16).
// ---------------------------------------------------------------------------
__global__ void prep_B(const float* __restrict__ w1, const float* __restrict__ root2,
                       const float* __restrict__ w2,
                       unsigned short* __restrict__ B1f, unsigned short* __restrict__ B2f) {
    int t = blockIdx.x * blockDim.x + threadIdx.x;
    if (t < 4 * 8 * 64 * 8) {
        int i = t & 7, l = (t >> 3) & 63, kt = (t >> 9) & 7, nt = t >> 12;
        int k = kt * 32 + ((l >> 4) * 8) + i;
        int col = nt * 16 + (l & 15);
        float v = (k < 64) ? root2[k * 64 + col] : w2[(k - 64) * 64 + col];
        B2f[t] = f2bf(v);
    }
    if (t < 4 * 3 * 64 * 8) {
        int i = t & 7, l = (t >> 3) & 63;
        int rest = t >> 9;
        int kt = rest % 3, nt = rest / 3;
        int k = kt * 32 + ((l >> 4) * 8) + i;
        int col = nt * 16 + (l & 15);
        B1f[t] = f2bf(w1[k * 64 + col]);
    }
}

// K3: combo[i] as u8
__global__ void combo_kernel(const int* __restrict__ node_x, unsigned char* __restrict__ combo, int N) {
    int i = blockIdx.x * blockDim.x + threadIdx.x;
    if (i < N) combo[i] = (unsigned char)(node_x[2 * i] * 8 + node_x[2 * i + 1]);
}

// ---------------------------------------------------------------------------
// K4 (pass A0): per-block bucket histogram. hist[b*NBLK_A + blk]
// ---------------------------------------------------------------------------
__global__ void __launch_bounds__(256) hist_kernel(const int* __restrict__ ei,
                                                   int* __restrict__ hist, int E, int NB, int chunk) {
    __shared__ int lh[256];
    for (int t = threadIdx.x; t < NB; t += 256) lh[t] = 0;
    __syncthreads();
    int s = blockIdx.x * chunk, e1 = min(E, s + chunk);
    for (int e = s + threadIdx.x; e < e1; e += 256)
        atomicAdd(&lh[ei[E + e] >> BSH], 1);
    __syncthreads();
    for (int b = threadIdx.x; b < NB; b += 256) hist[b * NBLK_A + blockIdx.x] = lh[b];
}

// generic exclusive scan (3 kernels)
__global__ void scan1(const int* __restrict__ in, int* __restrict__ out,
                      int* __restrict__ bsums, int n) {
    __shared__ int s[1024];
    int i = blockIdx.x * 1024 + threadIdx.x;
    int d = (i < n) ? in[i] : 0;
    s[threadIdx.x] = d;
    __syncthreads();
    for (int off = 1; off < 1024; off <<= 1) {
        int v = (threadIdx.x >= off) ? s[threadIdx.x - off] : 0;
        __syncthreads();
        s[threadIdx.x] += v;
        __syncthreads();
    }
    if (i < n) out[i] = s[threadIdx.x] - d;
    if (threadIdx.x == 1023) bsums[blockIdx.x] = s[1023];
}
__global__ void scan2(int* __restrict__ bsums, int nb) {
    __shared__ int s[128];
    int v = (threadIdx.x < nb) ? bsums[threadIdx.x] : 0;
    s[threadIdx.x] = v;
    __syncthreads();
    for (int off = 1; off < 128; off <<= 1) {
        int u = (threadIdx.x >= off) ? s[threadIdx.x - off] : 0;
        __syncthreads();
        s[threadIdx.x] += u;
        __syncthreads();
    }
    if (threadIdx.x < nb) bsums[threadIdx.x] = s[threadIdx.x] - v;
}
__global__ void scan3(int* __restrict__ out, const int* __restrict__ bsums, int n) {
    int i = blockIdx.x * 1024 + threadIdx.x;
    if (i < n) out[i] += bsums[blockIdx.x];
}

// ---------------------------------------------------------------------------
// K5 (pass A1): place edges into dst-buckets. entry = dloc<<19 | rel<<17 | src
// ---------------------------------------------------------------------------
__global__ void __launch_bounds__(256) place_kernel(const int* __restrict__ ei, const int* __restrict__ et,
                                                    const int* __restrict__ off, unsigned* __restrict__ staged,
                                                    int E, int NB, int chunk) {
    __shared__ int lh[256];
    for (int t = threadIdx.x; t < NB; t += 256) lh[t] = 0;
    __syncthreads();
    int s = blockIdx.x * chunk, e1 = min(E, s + chunk);
    for (int e = s + threadIdx.x; e < e1; e += 256) {
        int d = ei[E + e];
        int b = d >> BSH;
        int lr = atomicAdd(&lh[b], 1);
        int pos = off[b * NBLK_A + blockIdx.x] + lr;
        staged[pos] = ((unsigned)(d & (BNODES - 1)) << 19) | ((unsigned)et[e] << 17) | (unsigned)ei[e];
    }
}

// ---------------------------------------------------------------------------
// K6 (pass B): per-bucket finalize. LDS count -> block scan -> base3 write ->
// place into rel-segmented CSR. Final entry = combo<<17 | src.
// ---------------------------------------------------------------------------
__global__ void __launch_bounds__(256) finalize_kernel(
        const unsigned* __restrict__ staged, const int* __restrict__ off,
        const unsigned char* __restrict__ combo, unsigned* __restrict__ edges,
        int* __restrict__ base3, int E, int N, int NB) {
    __shared__ int lcnt[BNODES * 3];
    __shared__ int part[256];
    int blk = blockIdx.x;
    int d0 = blk * BNODES;
    int nn = min(BNODES, N - d0);
    int estart = off[blk * NBLK_A];
    int eend = (blk == NB - 1) ? E : off[(blk + 1) * NBLK_A];
    for (int t = threadIdx.x; t < BNODES * 3; t += 256) lcnt[t] = 0;
    __syncthreads();
    for (int e = estart + threadIdx.x; e < eend; e += 256) {
        unsigned p = staged[e];
        atomicAdd(&lcnt[(p >> 19) * 3 + ((p >> 17) & 3)], 1);
    }
    __syncthreads();
    // exclusive block scan of lcnt[0..1536), 6 elems/thread, offset by estart
    int t = threadIdx.x;
    int v0 = lcnt[t * 6], v1 = lcnt[t * 6 + 1], v2 = lcnt[t * 6 + 2];
    int v3 = lcnt[t * 6 + 3], v4 = lcnt[t * 6 + 4], v5 = lcnt[t * 6 + 5];
    int sum = v0 + v1 + v2 + v3 + v4 + v5;
    part[t] = sum;
    __syncthreads();
    for (int o = 1; o < 256; o <<= 1) {
        int u = (t >= o) ? part[t - o] : 0;
        __syncthreads();
        part[t] += u;
        __syncthreads();
    }
    int run = estart + part[t] - sum;
    lcnt[t * 6] = run; run += v0;
    lcnt[t * 6 + 1] = run; run += v1;
    lcnt[t * 6 + 2] = run; run += v2;
    lcnt[t * 6 + 3] = run; run += v3;
    lcnt[t * 6 + 4] = run; run += v4;
    lcnt[t * 6 + 5] = run;
    __syncthreads();
    for (int j = threadIdx.x; j < nn * 3; j += 256) base3[d0 * 3 + j] = lcnt[j];
    if (blk == NB - 1 && threadIdx.x == 0) base3[(size_t)N * 3] = E;
    __syncthreads();
    for (int e = estart + threadIdx.x; e < eend; e += 256) {
        unsigned p = staged[e];
        int src = p & 0x1FFFF;
        int slot = atomicAdd(&lcnt[(p >> 19) * 3 + ((p >> 17) & 3)], 1);
        edges[slot] = (unsigned)src | ((unsigned)combo[src] << 17);
    }
}

// ---------------------------------------------------------------------------
// K7: conv1 aggregation — fully coalesced (combo embedded in edge word).
// ---------------------------------------------------------------------------
__global__ void __launch_bounds__(256) agg1_kernel(
        const unsigned* __restrict__ edges, const int* __restrict__ base3,
        const float* __restrict__ x1tab, unsigned short* __restrict__ AGG1, int N) {
    __shared__ float tab[64 * 32];
    for (int t = threadIdx.x; t < 64 * 32; t += 256) tab[t] = x1tab[t];
    __syncthreads();
    int i = blockIdx.x * 4 + (threadIdx.x >> 6);
    if (i >= N) return;
    int lane = threadIdx.x & 63;
    int k = lane & 31, half = lane >> 5;
    int b0 = base3[i * 3], b1 = base3[i * 3 + 1], b2 = base3[i * 3 + 2], b3 = base3[i * 3 + 3];
    float a0 = 0.f, a1 = 0.f, a2 = 0.f;
    for (int e = b0 + half; e < b1; e += 2) a0 += tab[(edges[e] >> 17) * 32 + k];
    for (int e = b1 + half; e < b2; e += 2) a1 += tab[(edges[e] >> 17) * 32 + k];
    for (int e = b2 + half; e < b3; e += 2) a2 += tab[(edges[e] >> 17) * 32 + k];
    a0 += __shfl_xor(a0, 32);
    a1 += __shfl_xor(a1, 32);
    a2 += __shfl_xor(a2, 32);
    if (half == 0) {
        int l0 = b1 - b0, l1 = b2 - b1, l2 = b3 - b2;
        AGG1[(size_t)i * 96 + k]      = f2bf(a0 * (l0 > 0 ? 1.f / l0 : 0.f));
        AGG1[(size_t)i * 96 + 32 + k] = f2bf(a1 * (l1 > 0 ? 1.f / l1 : 0.f));
        AGG1[(size_t)i * 96 + 64 + k] = f2bf(a2 * (l2 > 0 ? 1.f / l2 : 0.f));
    }
}

// ---------------------------------------------------------------------------
// K8: conv1 transform. MFMA [16,96]@[96,64] + root-table epilogue -> h1 bf16
// ---------------------------------------------------------------------------
__global__ void __launch_bounds__(256) gemm1_kernel(
        const unsigned short* __restrict__ AGG1, const unsigned short* __restrict__ B1f,
        const float* __restrict__ root1t, const unsigned char* __restrict__ combo,
        unsigned short* __restrict__ h1, int N) {
    int g = blockIdx.x * 4 + (threadIdx.x >> 6);
    int node0 = g * 16;
    if (node0 >= N) return;
    int lane = threadIdx.x & 63;
    int m = lane & 15, kg = lane >> 4;
    short8 a[3];
#pragma unroll
    for (int kt = 0; kt < 3; ++kt)
        a[kt] = *(const short8*)(AGG1 + (size_t)(node0 + m) * 96 + kt * 32 + kg * 8);
#pragma unroll
    for (int nt = 0; nt < 4; ++nt) {
        floatx4 c = {0.f, 0.f, 0.f, 0.f};
#pragma unroll
        for (int kt = 0; kt < 3; ++kt) {
            short8 b = *(const short8*)(B1f + ((nt * 3 + kt) * 64 + lane) * 8);
            c = __builtin_amdgcn_mfma_f32_16x16x32_bf16(a[kt], b, c, 0, 0, 0);
        }
#pragma unroll
        for (int q = 0; q < 4; ++q) {
            int node = node0 + kg * 4 + q;
            int cc = combo[node] & 63;
            float v = c[q] + root1t[cc * 64 + nt * 16 + m];
            v = v > 0.f ? v : 0.f;
            h1[(size_t)node * 64 + nt * 16 + m] = f2bf(v);
        }
    }
}

// ---------------------------------------------------------------------------
// K9: conv2 aggregation. Wave per node, lane = dim; rel-segmented loop.
// ---------------------------------------------------------------------------
__global__ void __launch_bounds__(256) agg2_kernel(
        const unsigned* __restrict__ edges, const int* __restrict__ base3,
        const unsigned short* __restrict__ h1, unsigned short* __restrict__ AGG2, int N) {
    int i = blockIdx.x * 4 + (threadIdx.x >> 6);
    if (i >= N) return;
    int lane = threadIdx.x & 63;
    int b[4];
    b[0] = base3[i * 3]; b[1] = base3[i * 3 + 1];
    b[2] = base3[i * 3 + 2]; b[3] = base3[i * 3 + 3];
#pragma unroll
    for (int r = 0; r < 3; ++r) {
        int s = b[r], t = b[r + 1];
        float a = 0.f;
        int e = s;
        for (; e + 2 <= t; e += 2) {
            int s0 = edges[e] & 0x1FFFF, s1 = edges[e + 1] & 0x1FFFF;
            a += bf2f(h1[(size_t)s0 * 64 + lane]);
            a += bf2f(h1[(size_t)s1 * 64 + lane]);
        }
        if (e < t) a += bf2f(h1[(size_t)(edges[e] & 0x1FFFF) * 64 + lane]);
        int len = t - s;
        AGG2[(size_t)i * 192 + r * 64 + lane] = f2bf(a * (len > 0 ? 1.f / len : 0.f));
    }
}

// ---------------------------------------------------------------------------
// K10: conv2 transform. MFMA [16,256]@[256,64] -> h2 bf16
// ---------------------------------------------------------------------------
__global__ void __launch_bounds__(256) gemm2_kernel(
        const unsigned short* __restrict__ h1, const unsigned short* __restrict__ AGG2,
        const unsigned short* __restrict__ B2f, const float* __restrict__ b2,
        unsigned short* __restrict__ h2, int N) {
    int g = blockIdx.x * 4 + (threadIdx.x >> 6);
    int node0 = g * 16;
    if (node0 >= N) return;
    int lane = threadIdx.x & 63;
    int m = lane & 15, kg = lane >> 4;
    short8 a[8];
#pragma unroll
    for (int kt = 0; kt < 2; ++kt)
        a[kt] = *(const short8*)(h1 + (size_t)(node0 + m) * 64 + kt * 32 + kg * 8);
#pragma unroll
    for (int kt = 2; kt < 8; ++kt)
        a[kt] = *(const short8*)(AGG2 + (size_t)(node0 + m) * 192 + (kt - 2) * 32 + kg * 8);
#pragma unroll
    for (int nt = 0; nt < 4; ++nt) {
        floatx4 c = {0.f, 0.f, 0.f, 0.f};
#pragma unroll
        for (int kt = 0; kt < 8; ++kt) {
            short8 b = *(const short8*)(B2f + ((nt * 8 + kt) * 64 + lane) * 8);
            c = __builtin_amdgcn_mfma_f32_16x16x32_bf16(a[kt], b, c, 0, 0, 0);
        }
        float bias = b2[nt * 16 + m];
#pragma unroll
        for (int q = 0; q < 4; ++q) {
            int node = node0 + kg * 4 + q;
            h2[(size_t)node * 64 + nt * 16 + m] = f2bf(c[q] + bias);
        }
    }
}

// ---------------------------------------------------------------------------
// K11: mean-pool + classifier (relu folded)
// ---------------------------------------------------------------------------
__global__ void __launch_bounds__(64) pool_cls(
        const unsigned short* __restrict__ h2, const int* __restrict__ batch,
        const float* __restrict__ cls_w, const float* __restrict__ cls_b,
        float* __restrict__ out, int N, int G) {
    int g = blockIdx.x, lane = threadIdx.x;
    auto lb = [&](int key) {
        int lo = 0, hi = N;
        while (lo < hi) { int mid = (lo + hi) >> 1; if (batch[mid] < key) lo = mid + 1; else hi = mid; }
        return lo;
    };
    int start = lb(g), end = lb(g + 1);
    float sum = 0.f;
    for (int i = start; i < end; ++i) {
        float v = bf2f(h2[(size_t)i * 64 + lane]);
        sum += v > 0.f ? v : 0.f;
    }
    int cntn = end - start;
    float pooled = sum / (float)(cntn > 0 ? cntn : 1);
    __shared__ float ps[64];
    ps[lane] = pooled;
    __syncthreads();
    if (lane < 10) {
        float o = cls_b[lane];
#pragma unroll
        for (int j = 0; j < 64; ++j) o = fmaf(ps[j], cls_w[j * 10 + lane], o);
        out[g * 10 + lane] = o;
    }
}

// ---------------------------------------------------------------------------
extern "C" void kernel_launch(void* const* d_in, const int* in_sizes, int n_in,
                              void* d_out, int out_size, void* d_ws, size_t ws_size,
                              hipStream_t stream) {
    const int*   node_x = (const int*)d_in[0];
    const int*   ei     = (const int*)d_in[1];
    const int*   et     = (const int*)d_in[2];
    const int*   batch  = (const int*)d_in[3];
    const float* pre_w  = (const float*)d_in[4];
    const float* pre_b  = (const float*)d_in[5];
    const float* w1     = (const float*)d_in[6];
    const float* root1  = (const float*)d_in[7];
    const float* b1     = (const float*)d_in[8];
    const float* w2     = (const float*)d_in[9];
    const float* root2  = (const float*)d_in[10];
    const float* b2     = (const float*)d_in[11];
    const float* cls_w  = (const float*)d_in[12];
    const float* cls_b  = (const float*)d_in[13];
    float* out = (float*)d_out;

    int N = in_sizes[0] / 2;
    int E = in_sizes[1] / 2;
    int G = out_size / 10;

    int NB = (N + BNODES - 1) >> BSH;          // 196 buckets
    int chunk = (E + NBLK_A - 1) / NBLK_A;     // edges per hist/place block
    int nh = NB * NBLK_A;                      // hist length
    int nscan = (nh + 1023) / 1024;

    char* ws = (char*)d_ws;
    size_t off_b = 0;
    auto alloc = [&](size_t bytes) {
        void* p = ws + off_b;
        off_b = (off_b + bytes + 255) & ~(size_t)255;
        return p;
    };
    float*          x1tab  = (float*)alloc(64 * 32 * sizeof(float));
    float*          root1t = (float*)alloc(64 * 64 * sizeof(float));
    unsigned short* B1f    = (unsigned short*)alloc(4 * 3 * 64 * 8 * sizeof(short));
    unsigned short* B2f    = (unsigned short*)alloc(4 * 8 * 64 * 8 * sizeof(short));
    unsigned char*  combo  = (unsigned char*)alloc((size_t)N + 64);
    int*            hist   = (int*)alloc((size_t)nh * sizeof(int));
    int*            hoff   = (int*)alloc((size_t)nh * sizeof(int));
    int*            bsums  = (int*)alloc(128 * sizeof(int));
    unsigned*       staged = (unsigned*)alloc((size_t)E * sizeof(unsigned));
    unsigned*       edges  = (unsigned*)alloc((size_t)E * sizeof(unsigned));
    int*            base3  = (int*)alloc(((size_t)N * 3 + 8) * sizeof(int));
    unsigned short* h1     = (unsigned short*)alloc((size_t)(N + 16) * 64 * sizeof(short));
    unsigned short* h2     = (unsigned short*)alloc((size_t)(N + 16) * 64 * sizeof(short));
    unsigned short* AGGbuf = (unsigned short*)alloc((size_t)(N + 16) * 192 * sizeof(short));
    unsigned short* AGG1 = AGGbuf;   // [N+16][96]  (dead before AGG2 written)
    unsigned short* AGG2 = AGGbuf;   // [N+16][192]

    build_tables<<<64, 64, 0, stream>>>(pre_w, pre_b, root1, b1, x1tab, root1t);
    prep_B<<<64, 256, 0, stream>>>(w1, root2, w2, B1f, B2f);
    combo_kernel<<<(N + 255) / 256, 256, 0, stream>>>(node_x, combo, N);

    hist_kernel<<<NBLK_A, 256, 0, stream>>>(ei, hist, E, NB, chunk);
    scan1<<<nscan, 1024, 0, stream>>>(hist, hoff, bsums, nh);
    scan2<<<1, 128, 0, stream>>>(bsums, nscan);
    scan3<<<nscan, 1024, 0, stream>>>(hoff, bsums, nh);
    place_kernel<<<NBLK_A, 256, 0, stream>>>(ei, et, hoff, staged, E, NB, chunk);
    finalize_kernel<<<NB, 256, 0, stream>>>(staged, hoff, combo, edges, base3, E, N, NB);

    agg1_kernel<<<(N + 3) / 4, 256, 0, stream>>>(edges, base3, x1tab, AGG1, N);
    gemm1_kernel<<<((N + 15) / 16 + 3) / 4, 256, 0, stream>>>(AGG1, B1f, root1t, combo, h1, N);
    agg2_kernel<<<(N + 3) / 4, 256, 0, stream>>>(edges, base3, h1, AGG2, N);
    gemm2_kernel<<<((N + 15) / 16 + 3) / 4, 256, 0, stream>>>(h1, AGG2, B2f, b2, h2, N);
    pool_cls<<<G, 64, 0, stream>>>(h2, batch, cls_w, cls_b, out, N, G);
}